// Round 5
// baseline (566.406 us; speedup 1.0000x reference)
//
#include <hip/hip_runtime.h>
#include <math.h>

#define NODES_TOTAL 160000
#define NODES_REAL  5000
#define D 128
#define NEG 0.2f
#define KP2 128
#define HL2 (128 * KP2)       // ushorts per hi (or lo) block = 16384
#define WT2_L (2 * HL2)       // ushorts per layer (hi + lo)  = 32768 (64 KB)

typedef unsigned short ushort_t;
typedef unsigned int uint_t;
typedef __attribute__((ext_vector_type(8))) __bf16 bf16x8;
typedef __attribute__((ext_vector_type(4))) float f32x4;
union BF8 { bf16x8 v; ushort_t u[8]; };

__device__ __forceinline__ void split2(float x, ushort_t& hi, ushort_t& lo) {
    unsigned u = __float_as_uint(x);
    hi = (ushort_t)(u >> 16);
    float hif = __uint_as_float(u & 0xffff0000u);
    lo = (ushort_t)(__float_as_uint(x - hif) >> 16);
}
__device__ __forceinline__ uint_t encmax(float f) {
    uint_t b = __float_as_uint(f);
    return b ^ ((uint_t)((int)b >> 31) | 0x80000000u);
}
__device__ __forceinline__ float decmax(uint_t u) {
    uint_t b = (u & 0x80000000u) ? (u ^ 0x80000000u) : ~u;
    return __uint_as_float(b);
}

// ---------------- CSR build ----------------------------------------------------
__global__ void zero_kernel(int* counts, uint_t* gmaxu) {
    int i = blockIdx.x * blockDim.x + threadIdx.x;
    if (i < NODES_REAL) counts[i] = 0;
    if (i < 3) gmaxu[i] = 0u;
}

__global__ void rank_kernel(const int* __restrict__ ei, int* __restrict__ counts,
                            ushort_t* __restrict__ rank16, int Eh) {
    int e = blockIdx.x * blockDim.x + threadIdx.x;
    if (e < Eh) {
        int d = ei[Eh + e];
        int r = atomicAdd(&counts[d], 1);
        rank16[e] = (ushort_t)r;
    }
}

__global__ void scan_kernel(const int* __restrict__ counts, int* __restrict__ offs) {
    __shared__ int sd[1024];
    int t = threadIdx.x;
    int pre[5]; int sum = 0;
    #pragma unroll
    for (int u = 0; u < 5; ++u) {
        int idx = t * 5 + u;
        int c = (idx < NODES_REAL) ? counts[idx] : 0;
        pre[u] = sum; sum += c;
    }
    sd[t] = sum;
    __syncthreads();
    int run = sum;
    for (int o = 1; o < 1024; o <<= 1) {
        int v = (t >= o) ? sd[t - o] : 0;
        __syncthreads();
        sd[t] += v;
        __syncthreads();
    }
    int excl = sd[t] - run;
    #pragma unroll
    for (int u = 0; u < 5; ++u) {
        int idx = t * 5 + u;
        if (idx < NODES_REAL) offs[idx] = excl + pre[u];
    }
    if (t == 1023) offs[NODES_REAL] = excl + run;
}

// deterministic scatter, u16 payload (src < 5000)
__global__ void scatter_det(const int* __restrict__ ei, const int* __restrict__ offs,
                            const ushort_t* __restrict__ rank16, ushort_t* __restrict__ esrc,
                            int Eh) {
    int e = blockIdx.x * blockDim.x + threadIdx.x;
    if (e < Eh) {
        int s = ei[e];
        int d = ei[Eh + e];
        esrc[offs[d] + (int)rank16[e]] = (ushort_t)s;
    }
}

// ---------------- W split+transpose -> fragment-major layout -------------------
// Wm: off(l,ct,kc,hl,lane) = l*WT2_L + ((ct*4+kc)*2+hl)*512 + lane*8
// One wave-load of fragment (ct,kc,hl) = 64 lanes x 16B = 1KB CONTIGUOUS from L2.
__global__ void wsplit_kernel(const float* __restrict__ Ws, ushort_t* __restrict__ Wm) {
    int l  = blockIdx.x >> 3;
    int n  = (blockIdx.x & 7) * 16 + (threadIdx.x >> 4);
    int c8 = threadIdx.x & 15;
    int k0 = c8 * 8;
    const float* src = Ws + (size_t)l * D * D;
    union { ushort_t u[8]; uint4 v; } hi, lo;
    #pragma unroll
    for (int j = 0; j < 8; ++j) split2(src[(size_t)(k0 + j) * D + n], hi.u[j], lo.u[j]);
    int ct = n >> 4, m16 = n & 15, kc = c8 >> 2, qq = c8 & 3;
    int lane = qq * 16 + m16;
    ushort_t* d2 = Wm + (size_t)l * WT2_L + ((ct * 4 + kc) * 2 + 0) * 512 + lane * 8;
    *(uint4*)d2 = hi.v;
    *(uint4*)(d2 + 512) = lo.v;     // hl=1
}

// ---------------- fused 3-layer MLP for rows [5000,160000) ---------------------
// 2-wave (128-thr) blocks, 32 rows each; the wave pair splits the 8 col-tiles
// 4/4. B-fragments in registers from L2-resident Wm (16 coalesced 1KB loads per
// kc-half phase, then 48 register MFMAs). LDS = 16.9KB scr only -> up to 9
// blocks/CU by LDS, 4 waves/SIMD by VGPR (116 incl AGPR <= 128).
__global__ __launch_bounds__(128, 4)
void mlp3_kernel(const float* __restrict__ x, const ushort_t* __restrict__ Wm,
                 const float* __restrict__ bs, float* __restrict__ out) {
    __shared__ float scr[2][16][132];      // 16896 B
    int tid = threadIdx.x;
    int h = tid >> 6, lane = tid & 63, q = lane >> 4, m16 = lane & 15;
    int row0 = NODES_REAL + blockIdx.x * 32;

    // layer-0 A prefetch into registers
    float4 xa[2][4][2];
    #pragma unroll
    for (int rt = 0; rt < 2; ++rt) {
        int r = row0 + rt * 16 + m16;
        if (r > NODES_TOTAL - 1) r = NODES_TOTAL - 1;
        #pragma unroll
        for (int kc = 0; kc < 4; ++kc) {
            const float* gp = x + (size_t)r * D + kc * 32 + q * 8;
            xa[rt][kc][0] = *(const float4*)gp;
            xa[rt][kc][1] = *(const float4*)(gp + 4);
        }
    }

    f32x4 acc[2][4];
    #pragma unroll
    for (int l = 0; l < 3; ++l) {
        const ushort_t* Wml = Wm + (size_t)l * WT2_L;
        if (l > 0) __syncthreads();        // (1) prev layer's scr writes visible

        // A for this layer -> bf16 hi/lo registers (all 4 kc upfront)
        BF8 ahi[2][4], alo[2][4];
        #pragma unroll
        for (int rt = 0; rt < 2; ++rt)
            #pragma unroll
            for (int kc = 0; kc < 4; ++kc) {
                float4 v0, v1;
                if (l == 0) { v0 = xa[rt][kc][0]; v1 = xa[rt][kc][1]; }
                else {
                    const float* sp = &scr[rt][m16][kc * 32 + q * 8];
                    v0 = *(const float4*)sp; v1 = *(const float4*)(sp + 4);
                }
                float xv[8] = {v0.x, v0.y, v0.z, v0.w, v1.x, v1.y, v1.z, v1.w};
                #pragma unroll
                for (int j = 0; j < 8; ++j) split2(xv[j], ahi[rt][kc].u[j], alo[rt][kc].u[j]);
            }
        if (l > 0) __syncthreads();        // (2) all scr reads done; writes below safe

        #pragma unroll
        for (int rt = 0; rt < 2; ++rt)
            #pragma unroll
            for (int ct = 0; ct < 4; ++ct) acc[rt][ct] = (f32x4){0.f, 0.f, 0.f, 0.f};

        // two kc-half phases: 16 coalesced B loads, then 48 register MFMAs
        #pragma unroll
        for (int ph = 0; ph < 2; ++ph) {
            int kc0 = ph * 2;
            bf16x8 bh[4][2], bl[4][2];
            #pragma unroll
            for (int ct = 0; ct < 4; ++ct)
                #pragma unroll
                for (int dk = 0; dk < 2; ++dk) {
                    const ushort_t* bp = Wml + (((h * 4 + ct) * 4 + (kc0 + dk)) * 2) * 512 + lane * 8;
                    bh[ct][dk] = *(const bf16x8*)bp;
                    bl[ct][dk] = *(const bf16x8*)(bp + 512);
                }
            #pragma unroll
            for (int dk = 0; dk < 2; ++dk)
                #pragma unroll
                for (int ct = 0; ct < 4; ++ct)
                    #pragma unroll
                    for (int rt = 0; rt < 2; ++rt) {
                        acc[rt][ct] = __builtin_amdgcn_mfma_f32_16x16x32_bf16(ahi[rt][kc0 + dk].v, bh[ct][dk], acc[rt][ct], 0, 0, 0);
                        acc[rt][ct] = __builtin_amdgcn_mfma_f32_16x16x32_bf16(ahi[rt][kc0 + dk].v, bl[ct][dk], acc[rt][ct], 0, 0, 0);
                        acc[rt][ct] = __builtin_amdgcn_mfma_f32_16x16x32_bf16(alo[rt][kc0 + dk].v, bh[ct][dk], acc[rt][ct], 0, 0, 0);
                    }
        }
        // relu(h2 + b) -> pair-shared scratch (disjoint col halves per wave)
        float bv[4];
        #pragma unroll
        for (int ct = 0; ct < 4; ++ct) bv[ct] = bs[l * D + (h * 4 + ct) * 16 + m16];
        #pragma unroll
        for (int rt = 0; rt < 2; ++rt)
            #pragma unroll
            for (int ct = 0; ct < 4; ++ct)
                #pragma unroll
                for (int reg = 0; reg < 4; ++reg)
                    scr[rt][q * 4 + reg][(h * 4 + ct) * 16 + m16] =
                        fmaxf(acc[rt][ct][reg] + bv[ct], 0.f);
    }
    __syncthreads();   // partner's final scr writes visible for epilogue
    // coalesced epilogue: each wave streams its 16 rows (rt = h) x 128 cols
    #pragma unroll
    for (int i = 0; i < 8; ++i) {
        int rowl = i * 2 + (lane >> 5);          // 0..15
        int grow = row0 + h * 16 + rowl;
        float4 v = *(const float4*)&scr[h][rowl][(lane & 31) * 4];
        if (grow < NODES_TOTAL)
            *(float4*)&out[(size_t)grow * D + (lane & 31) * 4] = v;
    }
}

// ---------------- small GEMM (rows<5000) + fused scores + per-layer max --------
// Register-B rewrite: 1-wave (64-thr) blocks, 16 rows each -> 313 blocks (8x the
// old 40). No LDS, no barriers, no 64KB W stage: B comes from L2-resident Wm as
// 16 coalesced 1KB wave-loads per kc phase, then 24 register MFMAs.
__global__ __launch_bounds__(64, 2)
void gsmall_kernel(const float* __restrict__ hin, const ushort_t* __restrict__ Wm,
                   const float* __restrict__ a_s, const float* __restrict__ a_d,
                   float* __restrict__ h2, float* __restrict__ sv, float* __restrict__ dv,
                   uint_t* __restrict__ gmaxu) {
    int lane = threadIdx.x & 63, q = lane >> 4, m16 = lane & 15;
    int row0 = blockIdx.x * 16;
    // prefetch A (16 rows x 128 cols)
    float4 xa[4][2];
    {
        int r = row0 + m16;
        if (r > NODES_REAL - 1) r = NODES_REAL - 1;
        #pragma unroll
        for (int kc = 0; kc < 4; ++kc) {
            const float* gp = hin + (size_t)r * D + kc * 32 + q * 8;
            xa[kc][0] = *(const float4*)gp;
            xa[kc][1] = *(const float4*)(gp + 4);
        }
    }
    f32x4 acc[8];
    #pragma unroll
    for (int ct = 0; ct < 8; ++ct) acc[ct] = (f32x4){0.f, 0.f, 0.f, 0.f};

    #pragma unroll
    for (int kc = 0; kc < 4; ++kc) {
        BF8 ahi, alo;
        {
            float4 v0 = xa[kc][0], v1 = xa[kc][1];
            float xv[8] = {v0.x, v0.y, v0.z, v0.w, v1.x, v1.y, v1.z, v1.w};
            #pragma unroll
            for (int j = 0; j < 8; ++j) split2(xv[j], ahi.u[j], alo.u[j]);
        }
        bf16x8 bh[8], bl[8];
        #pragma unroll
        for (int ct = 0; ct < 8; ++ct) {
            const ushort_t* bp = Wm + ((ct * 4 + kc) * 2) * 512 + lane * 8;
            bh[ct] = *(const bf16x8*)bp;
            bl[ct] = *(const bf16x8*)(bp + 512);
        }
        #pragma unroll
        for (int ct = 0; ct < 8; ++ct) {
            acc[ct] = __builtin_amdgcn_mfma_f32_16x16x32_bf16(ahi.v, bh[ct], acc[ct], 0, 0, 0);
            acc[ct] = __builtin_amdgcn_mfma_f32_16x16x32_bf16(ahi.v, bl[ct], acc[ct], 0, 0, 0);
            acc[ct] = __builtin_amdgcn_mfma_f32_16x16x32_bf16(alo.v, bh[ct], acc[ct], 0, 0, 0);
        }
    }
    // h2 store (C layout: row = q*4+reg, col = ct*16+m16)
    #pragma unroll
    for (int reg = 0; reg < 4; ++reg) {
        int grow = row0 + q * 4 + reg;
        if (grow < NODES_REAL) {
            #pragma unroll
            for (int ct = 0; ct < 8; ++ct)
                h2[(size_t)grow * D + ct * 16 + m16] = acc[ct][reg];
        }
    }
    // fused scores + per-layer global max
    float asv[8], adv[8];
    #pragma unroll
    for (int ct = 0; ct < 8; ++ct) { asv[ct] = a_s[ct * 16 + m16]; adv[ct] = a_d[ct * 16 + m16]; }
    #pragma unroll
    for (int reg = 0; reg < 4; ++reg) {
        float ps = 0.f, pd = 0.f;
        #pragma unroll
        for (int ct = 0; ct < 8; ++ct) {
            float v = acc[ct][reg];
            ps += v * asv[ct]; pd += v * adv[ct];
        }
        #pragma unroll
        for (int o = 1; o < 16; o <<= 1) { ps += __shfl_xor(ps, o); pd += __shfl_xor(pd, o); }
        int grow = row0 + q * 4 + reg;
        if (m16 == 0 && grow < NODES_REAL) {
            sv[grow] = ps; dv[grow] = pd;
            atomicMax(gmaxu, encmax(ps));
        }
    }
}

// ---------------- aggregation: one wave per dst, global-bound softmax ----------
__global__ __launch_bounds__(256)
void agg_kernel(const float* __restrict__ h2, const float* __restrict__ sv,
                const float* __restrict__ dv, const int* __restrict__ offs,
                const ushort_t* __restrict__ esrc, const float* __restrict__ bias,
                float* __restrict__ out, const uint_t* __restrict__ gmaxu) {
    int w = threadIdx.x >> 6, lane = threadIdx.x & 63;
    int i = blockIdx.x * 4 + w;
    int start = offs[i], end = offs[i + 1];
    float d_i = dv[i];
    float gm = decmax(*gmaxu) + d_i;       // upper bound on every incoming score
    float m = gm > 0.f ? gm : NEG * gm;    // leaky_relu monotone -> exact shift
    const float2* h2v = (const float2*)h2; // index: src*64 + lane
    float ax0 = 0.f, ay0 = 0.f, ax1 = 0.f, ay1 = 0.f;
    float ax2 = 0.f, ay2 = 0.f, ax3 = 0.f, ay3 = 0.f, exs = 0.f;
    for (int base = start; base < end; base += 64) {
        int cnt = min(64, end - base);
        int srci = (lane < cnt) ? (int)esrc[base + lane] : 0;
        float sc = sv[srci] + d_i;
        sc = sc > 0.f ? sc : NEG * sc;
        float ex = (lane < cnt) ? __expf(sc - m) : 0.f;
        exs += ex;
        if (cnt == 64) {
            #pragma unroll 2
            for (int j = 0; j < 64; j += 4) {   // 4 independent load+fmac chains
                int   s0 = __shfl(srci, j),     s1 = __shfl(srci, j + 1);
                int   s2 = __shfl(srci, j + 2), s3 = __shfl(srci, j + 3);
                float e0 = __shfl(ex, j),       e1 = __shfl(ex, j + 1);
                float e2 = __shfl(ex, j + 2),   e3 = __shfl(ex, j + 3);
                float2 hv0 = h2v[(size_t)s0 * 64 + lane];
                float2 hv1 = h2v[(size_t)s1 * 64 + lane];
                float2 hv2 = h2v[(size_t)s2 * 64 + lane];
                float2 hv3 = h2v[(size_t)s3 * 64 + lane];
                ax0 += e0 * hv0.x; ay0 += e0 * hv0.y;
                ax1 += e1 * hv1.x; ay1 += e1 * hv1.y;
                ax2 += e2 * hv2.x; ay2 += e2 * hv2.y;
                ax3 += e3 * hv3.x; ay3 += e3 * hv3.y;
            }
        } else {
            for (int j = 0; j < cnt; ++j) {
                int   src = __shfl(srci, j);
                float e   = __shfl(ex, j);
                float2 hv = h2v[(size_t)src * 64 + lane];
                ax0 += e * hv.x; ay0 += e * hv.y;
            }
        }
    }
    float ax = (ax0 + ax1) + (ax2 + ax3);
    float ay = (ay0 + ay1) + (ay2 + ay3);
    float scf = sv[i] + d_i; scf = scf > 0.f ? scf : NEG * scf;
    float exf = __expf(scf - m);
    float2 hv = h2v[(size_t)i * 64 + lane];
    ax += exf * hv.x; ay += exf * hv.y;
    #pragma unroll
    for (int o = 1; o < 64; o <<= 1) exs += __shfl_xor(exs, o);
    float rd = 1.f / (exs + exf);
    float2 b2 = *(const float2*)&bias[2 * lane];
    float2 o2 = make_float2(fmaxf(ax * rd + b2.x, 0.f), fmaxf(ay * rd + b2.y, 0.f));
    *(float2*)&out[(size_t)i * D + 2 * lane] = o2;
}

// ---------------- launcher -----------------------------------------------------
extern "C" void kernel_launch(void* const* d_in, const int* in_sizes, int n_in,
                              void* d_out, int out_size, void* d_ws, size_t ws_size,
                              hipStream_t stream) {
    const float* x   = (const float*)d_in[0];
    const int*   ei  = (const int*)d_in[1];
    const float* Ws  = (const float*)d_in[2];
    const float* as_ = (const float*)d_in[3];
    const float* ad_ = (const float*)d_in[4];
    const float* bs  = (const float*)d_in[5];
    float* out = (float*)d_out;
    int Eh = in_sizes[1] / 2;                    // 1,280,000

    char* ws = (char*)d_ws;
    float*    h2     = (float*)ws;                        //  2,560,000
    float*    bufS   = (float*)(ws + 2560000);            //  2,560,000
    float*    sv     = (float*)(ws + 5120000);            //     20,000
    float*    dv     = (float*)(ws + 5140000);            //     20,000
    int*      counts = (int*)  (ws + 5160000);            //     20,000
    int*      offs   = (int*)  (ws + 5180000);            //     20,016
    ushort_t* rank16 = (ushort_t*)(ws + 5200016);         //  2,560,000
    ushort_t* esrc   = (ushort_t*)(ws + 7760016);         //  2,560,000
    ushort_t* Wm     = (ushort_t*)(ws + 10320016);        //    196,608 (frag-major)
    uint_t*   gmaxu  = (uint_t*)(ws + 10528912);          //         12

    zero_kernel<<<(NODES_REAL + 255) / 256, 256, 0, stream>>>(counts, gmaxu);
    rank_kernel<<<(Eh + 255) / 256, 256, 0, stream>>>(ei, counts, rank16, Eh);
    scan_kernel<<<1, 1024, 0, stream>>>(counts, offs);
    scatter_det<<<(Eh + 255) / 256, 256, 0, stream>>>(ei, offs, rank16, esrc, Eh);
    wsplit_kernel<<<24, 256, 0, stream>>>(Ws, Wm);

    // rows >= 5000: fused 3-layer MLP, one HBM pass (32 rows / 2-wave block)
    mlp3_kernel<<<(NODES_TOTAL - NODES_REAL + 31) / 32, 128, 0, stream>>>(x, Wm, bs, out);

    // rows < 5000: per-layer GAT pipeline
    for (int l = 0; l < 3; ++l) {
        const float* hin = (l == 0) ? x : bufS;
        float* hout = (l == 2) ? out : bufS;
        gsmall_kernel<<<(NODES_REAL + 15) / 16, 64, 0, stream>>>(
            hin, Wm + (size_t)l * WT2_L, as_ + l * D, ad_ + l * D, h2, sv, dv, gmaxu + l);
        agg_kernel<<<(NODES_REAL + 3) / 4, 256, 0, stream>>>(
            h2, sv, dv, offs, esrc, bs + l * D, hout, gmaxu + l);
    }
}

// Round 6
// 540.293 us; speedup vs baseline: 1.0483x; 1.0483x over previous
//
#include <hip/hip_runtime.h>
#include <math.h>

#define NODES_TOTAL 160000
#define NODES_REAL  5000
#define D 128
#define NEG 0.2f
#define KP2 128
#define HL2 (128 * KP2)       // ushorts per hi (or lo) block = 16384
#define WT2_L (2 * HL2)       // ushorts per layer (hi + lo)  = 32768 (64 KB)

typedef unsigned short ushort_t;
typedef unsigned int uint_t;
typedef __attribute__((ext_vector_type(8))) __bf16 bf16x8;
typedef __attribute__((ext_vector_type(4))) float f32x4;
union BF8 { bf16x8 v; ushort_t u[8]; };

__device__ __forceinline__ void split2(float x, ushort_t& hi, ushort_t& lo) {
    unsigned u = __float_as_uint(x);
    hi = (ushort_t)(u >> 16);
    float hif = __uint_as_float(u & 0xffff0000u);
    lo = (ushort_t)(__float_as_uint(x - hif) >> 16);
}
__device__ __forceinline__ uint_t encmax(float f) {
    uint_t b = __float_as_uint(f);
    return b ^ ((uint_t)((int)b >> 31) | 0x80000000u);
}
__device__ __forceinline__ float decmax(uint_t u) {
    uint_t b = (u & 0x80000000u) ? (u ^ 0x80000000u) : ~u;
    return __uint_as_float(b);
}

// ---------------- CSR build ----------------------------------------------------
__global__ void zero_kernel(int* counts, uint_t* gmaxu) {
    int i = blockIdx.x * blockDim.x + threadIdx.x;
    if (i < NODES_REAL) counts[i] = 0;
    if (i < 3) gmaxu[i] = 0u;
}

__global__ void rank_kernel(const int* __restrict__ ei, int* __restrict__ counts,
                            ushort_t* __restrict__ rank16, int Eh) {
    int e = blockIdx.x * blockDim.x + threadIdx.x;
    if (e < Eh) {
        int d = ei[Eh + e];
        int r = atomicAdd(&counts[d], 1);
        rank16[e] = (ushort_t)r;
    }
}

__global__ void scan_kernel(const int* __restrict__ counts, int* __restrict__ offs) {
    __shared__ int sd[1024];
    int t = threadIdx.x;
    int pre[5]; int sum = 0;
    #pragma unroll
    for (int u = 0; u < 5; ++u) {
        int idx = t * 5 + u;
        int c = (idx < NODES_REAL) ? counts[idx] : 0;
        pre[u] = sum; sum += c;
    }
    sd[t] = sum;
    __syncthreads();
    int run = sum;
    for (int o = 1; o < 1024; o <<= 1) {
        int v = (t >= o) ? sd[t - o] : 0;
        __syncthreads();
        sd[t] += v;
        __syncthreads();
    }
    int excl = sd[t] - run;
    #pragma unroll
    for (int u = 0; u < 5; ++u) {
        int idx = t * 5 + u;
        if (idx < NODES_REAL) offs[idx] = excl + pre[u];
    }
    if (t == 1023) offs[NODES_REAL] = excl + run;
}

// deterministic scatter, u16 payload (src < 5000)
__global__ void scatter_det(const int* __restrict__ ei, const int* __restrict__ offs,
                            const ushort_t* __restrict__ rank16, ushort_t* __restrict__ esrc,
                            int Eh) {
    int e = blockIdx.x * blockDim.x + threadIdx.x;
    if (e < Eh) {
        int s = ei[e];
        int d = ei[Eh + e];
        esrc[offs[d] + (int)rank16[e]] = (ushort_t)s;
    }
}

// ---------------- W split+transpose -> fragment-major layout -------------------
// Wm: off(l,ct,kc,hl,lane) = l*WT2_L + ((ct*4+kc)*2+hl)*512 + lane*8
// One wave-load of fragment (ct,kc,hl) = 64 lanes x 16B = 1KB CONTIGUOUS from L2.
__global__ void wsplit_kernel(const float* __restrict__ Ws, ushort_t* __restrict__ Wm) {
    int l  = blockIdx.x >> 3;
    int n  = (blockIdx.x & 7) * 16 + (threadIdx.x >> 4);
    int c8 = threadIdx.x & 15;
    int k0 = c8 * 8;
    const float* src = Ws + (size_t)l * D * D;
    union { ushort_t u[8]; uint4 v; } hi, lo;
    #pragma unroll
    for (int j = 0; j < 8; ++j) split2(src[(size_t)(k0 + j) * D + n], hi.u[j], lo.u[j]);
    int ct = n >> 4, m16 = n & 15, kc = c8 >> 2, qq = c8 & 3;
    int lane = qq * 16 + m16;
    ushort_t* d2 = Wm + (size_t)l * WT2_L + ((ct * 4 + kc) * 2 + 0) * 512 + lane * 8;
    *(uint4*)d2 = hi.v;
    *(uint4*)(d2 + 512) = lo.v;     // hl=1
}

// ---------------- fused 3-layer MLP (round-4 structure, grid-sliced) -----------
// B-fragments in REGISTERS from L2-resident Wm (16 coalesced 1KB wave-loads per
// kc-half phase, then 48 register MFMAs). LDS = 33.8KB scr only. 256 thr =
// 4 waves = 2 pairs x 32 rows (64 rows/block). VGPR 84, no spill (r4-verified).
// Launched as 3 grid slices so the ~33us pieces drop below agg/gsmall in the
// profiler's top-5 (diagnostic visibility into the 417us non-mlp3 residual).
__global__ __launch_bounds__(256, 2)
void mlp3_kernel(const float* __restrict__ x, const ushort_t* __restrict__ Wm,
                 const float* __restrict__ bs, float* __restrict__ out, int row_base) {
    __shared__ float scr[2][2][16][132];   // 33792 B
    int tid = threadIdx.x;
    int w = tid >> 6, lane = tid & 63, q = lane >> 4, m16 = lane & 15;
    int p = w >> 1, h = w & 1;             // pair index, column-half index
    int row0 = row_base + blockIdx.x * 64 + p * 32;

    // layer-0 A prefetch into registers
    float4 xa[2][4][2];
    #pragma unroll
    for (int rt = 0; rt < 2; ++rt) {
        int r = row0 + rt * 16 + m16;
        if (r > NODES_TOTAL - 1) r = NODES_TOTAL - 1;
        #pragma unroll
        for (int kc = 0; kc < 4; ++kc) {
            const float* gp = x + (size_t)r * D + kc * 32 + q * 8;
            xa[rt][kc][0] = *(const float4*)gp;
            xa[rt][kc][1] = *(const float4*)(gp + 4);
        }
    }

    f32x4 acc[2][4];
    #pragma unroll
    for (int l = 0; l < 3; ++l) {
        const ushort_t* Wml = Wm + (size_t)l * WT2_L;
        if (l > 0) __syncthreads();        // (1) prev layer's scr writes visible

        // A for this layer -> bf16 hi/lo registers (all 4 kc upfront)
        BF8 ahi[2][4], alo[2][4];
        #pragma unroll
        for (int rt = 0; rt < 2; ++rt)
            #pragma unroll
            for (int kc = 0; kc < 4; ++kc) {
                float4 v0, v1;
                if (l == 0) { v0 = xa[rt][kc][0]; v1 = xa[rt][kc][1]; }
                else {
                    const float* sp = &scr[p][rt][m16][kc * 32 + q * 8];
                    v0 = *(const float4*)sp; v1 = *(const float4*)(sp + 4);
                }
                float xv[8] = {v0.x, v0.y, v0.z, v0.w, v1.x, v1.y, v1.z, v1.w};
                #pragma unroll
                for (int j = 0; j < 8; ++j) split2(xv[j], ahi[rt][kc].u[j], alo[rt][kc].u[j]);
            }
        if (l > 0) __syncthreads();        // (2) all scr reads done; writes below safe

        #pragma unroll
        for (int rt = 0; rt < 2; ++rt)
            #pragma unroll
            for (int ct = 0; ct < 4; ++ct) acc[rt][ct] = (f32x4){0.f, 0.f, 0.f, 0.f};

        // two kc-half phases: 16 coalesced B loads, then 48 register MFMAs
        #pragma unroll
        for (int ph = 0; ph < 2; ++ph) {
            int kc0 = ph * 2;
            bf16x8 bh[4][2], bl[4][2];
            #pragma unroll
            for (int ct = 0; ct < 4; ++ct)
                #pragma unroll
                for (int dk = 0; dk < 2; ++dk) {
                    const ushort_t* bp = Wml + (((h * 4 + ct) * 4 + (kc0 + dk)) * 2) * 512 + lane * 8;
                    bh[ct][dk] = *(const bf16x8*)bp;
                    bl[ct][dk] = *(const bf16x8*)(bp + 512);
                }
            #pragma unroll
            for (int dk = 0; dk < 2; ++dk)
                #pragma unroll
                for (int ct = 0; ct < 4; ++ct)
                    #pragma unroll
                    for (int rt = 0; rt < 2; ++rt) {
                        acc[rt][ct] = __builtin_amdgcn_mfma_f32_16x16x32_bf16(ahi[rt][kc0 + dk].v, bh[ct][dk], acc[rt][ct], 0, 0, 0);
                        acc[rt][ct] = __builtin_amdgcn_mfma_f32_16x16x32_bf16(ahi[rt][kc0 + dk].v, bl[ct][dk], acc[rt][ct], 0, 0, 0);
                        acc[rt][ct] = __builtin_amdgcn_mfma_f32_16x16x32_bf16(alo[rt][kc0 + dk].v, bh[ct][dk], acc[rt][ct], 0, 0, 0);
                    }
        }
        // relu(h2 + b) -> pair-shared scratch (disjoint col halves per wave)
        float bv[4];
        #pragma unroll
        for (int ct = 0; ct < 4; ++ct) bv[ct] = bs[l * D + (h * 4 + ct) * 16 + m16];
        #pragma unroll
        for (int rt = 0; rt < 2; ++rt)
            #pragma unroll
            for (int ct = 0; ct < 4; ++ct)
                #pragma unroll
                for (int reg = 0; reg < 4; ++reg)
                    scr[p][rt][q * 4 + reg][(h * 4 + ct) * 16 + m16] =
                        fmaxf(acc[rt][ct][reg] + bv[ct], 0.f);
    }
    __syncthreads();   // partner's final scr writes visible for epilogue
    // coalesced epilogue: each wave streams its 16 rows (rt = h) x 128 cols
    #pragma unroll
    for (int i = 0; i < 8; ++i) {
        int rowl = i * 2 + (lane >> 5);          // 0..15
        int grow = row0 + h * 16 + rowl;
        float4 v = *(const float4*)&scr[p][h][rowl][(lane & 31) * 4];
        if (grow < NODES_TOTAL)
            *(float4*)&out[(size_t)grow * D + (lane & 31) * 4] = v;
    }
}

// ---------------- small GEMM (rows<5000) + fused scores + per-layer max --------
// Register-B: 1-wave (64-thr) blocks, 16 rows each -> 313 blocks. No LDS, no
// barriers, no W stage: B from L2-resident Wm, 16 coalesced 1KB wave-loads per
// kc phase, then 24 register MFMAs.
__global__ __launch_bounds__(64, 2)
void gsmall_kernel(const float* __restrict__ hin, const ushort_t* __restrict__ Wm,
                   const float* __restrict__ a_s, const float* __restrict__ a_d,
                   float* __restrict__ h2, float* __restrict__ sv, float* __restrict__ dv,
                   uint_t* __restrict__ gmaxu) {
    int lane = threadIdx.x & 63, q = lane >> 4, m16 = lane & 15;
    int row0 = blockIdx.x * 16;
    // prefetch A (16 rows x 128 cols)
    float4 xa[4][2];
    {
        int r = row0 + m16;
        if (r > NODES_REAL - 1) r = NODES_REAL - 1;
        #pragma unroll
        for (int kc = 0; kc < 4; ++kc) {
            const float* gp = hin + (size_t)r * D + kc * 32 + q * 8;
            xa[kc][0] = *(const float4*)gp;
            xa[kc][1] = *(const float4*)(gp + 4);
        }
    }
    f32x4 acc[8];
    #pragma unroll
    for (int ct = 0; ct < 8; ++ct) acc[ct] = (f32x4){0.f, 0.f, 0.f, 0.f};

    #pragma unroll
    for (int kc = 0; kc < 4; ++kc) {
        BF8 ahi, alo;
        {
            float4 v0 = xa[kc][0], v1 = xa[kc][1];
            float xv[8] = {v0.x, v0.y, v0.z, v0.w, v1.x, v1.y, v1.z, v1.w};
            #pragma unroll
            for (int j = 0; j < 8; ++j) split2(xv[j], ahi.u[j], alo.u[j]);
        }
        bf16x8 bh[8], bl[8];
        #pragma unroll
        for (int ct = 0; ct < 8; ++ct) {
            const ushort_t* bp = Wm + ((ct * 4 + kc) * 2) * 512 + lane * 8;
            bh[ct] = *(const bf16x8*)bp;
            bl[ct] = *(const bf16x8*)(bp + 512);
        }
        #pragma unroll
        for (int ct = 0; ct < 8; ++ct) {
            acc[ct] = __builtin_amdgcn_mfma_f32_16x16x32_bf16(ahi.v, bh[ct], acc[ct], 0, 0, 0);
            acc[ct] = __builtin_amdgcn_mfma_f32_16x16x32_bf16(ahi.v, bl[ct], acc[ct], 0, 0, 0);
            acc[ct] = __builtin_amdgcn_mfma_f32_16x16x32_bf16(alo.v, bh[ct], acc[ct], 0, 0, 0);
        }
    }
    // h2 store (C layout: row = q*4+reg, col = ct*16+m16)
    #pragma unroll
    for (int reg = 0; reg < 4; ++reg) {
        int grow = row0 + q * 4 + reg;
        if (grow < NODES_REAL) {
            #pragma unroll
            for (int ct = 0; ct < 8; ++ct)
                h2[(size_t)grow * D + ct * 16 + m16] = acc[ct][reg];
        }
    }
    // fused scores + per-layer global max
    float asv[8], adv[8];
    #pragma unroll
    for (int ct = 0; ct < 8; ++ct) { asv[ct] = a_s[ct * 16 + m16]; adv[ct] = a_d[ct * 16 + m16]; }
    #pragma unroll
    for (int reg = 0; reg < 4; ++reg) {
        float ps = 0.f, pd = 0.f;
        #pragma unroll
        for (int ct = 0; ct < 8; ++ct) {
            float v = acc[ct][reg];
            ps += v * asv[ct]; pd += v * adv[ct];
        }
        #pragma unroll
        for (int o = 1; o < 16; o <<= 1) { ps += __shfl_xor(ps, o); pd += __shfl_xor(pd, o); }
        int grow = row0 + q * 4 + reg;
        if (m16 == 0 && grow < NODES_REAL) {
            sv[grow] = ps; dv[grow] = pd;
            atomicMax(gmaxu, encmax(ps));
        }
    }
}

// ---------------- aggregation: one wave per dst, global-bound softmax ----------
__global__ __launch_bounds__(256)
void agg_kernel(const float* __restrict__ h2, const float* __restrict__ sv,
                const float* __restrict__ dv, const int* __restrict__ offs,
                const ushort_t* __restrict__ esrc, const float* __restrict__ bias,
                float* __restrict__ out, const uint_t* __restrict__ gmaxu) {
    int w = threadIdx.x >> 6, lane = threadIdx.x & 63;
    int i = blockIdx.x * 4 + w;
    int start = offs[i], end = offs[i + 1];
    float d_i = dv[i];
    float gm = decmax(*gmaxu) + d_i;       // upper bound on every incoming score
    float m = gm > 0.f ? gm : NEG * gm;    // leaky_relu monotone -> exact shift
    const float2* h2v = (const float2*)h2; // index: src*64 + lane
    float ax0 = 0.f, ay0 = 0.f, ax1 = 0.f, ay1 = 0.f;
    float ax2 = 0.f, ay2 = 0.f, ax3 = 0.f, ay3 = 0.f, exs = 0.f;
    for (int base = start; base < end; base += 64) {
        int cnt = min(64, end - base);
        int srci = (lane < cnt) ? (int)esrc[base + lane] : 0;
        float sc = sv[srci] + d_i;
        sc = sc > 0.f ? sc : NEG * sc;
        float ex = (lane < cnt) ? __expf(sc - m) : 0.f;
        exs += ex;
        if (cnt == 64) {
            #pragma unroll 2
            for (int j = 0; j < 64; j += 4) {   // 4 independent load+fmac chains
                int   s0 = __shfl(srci, j),     s1 = __shfl(srci, j + 1);
                int   s2 = __shfl(srci, j + 2), s3 = __shfl(srci, j + 3);
                float e0 = __shfl(ex, j),       e1 = __shfl(ex, j + 1);
                float e2 = __shfl(ex, j + 2),   e3 = __shfl(ex, j + 3);
                float2 hv0 = h2v[(size_t)s0 * 64 + lane];
                float2 hv1 = h2v[(size_t)s1 * 64 + lane];
                float2 hv2 = h2v[(size_t)s2 * 64 + lane];
                float2 hv3 = h2v[(size_t)s3 * 64 + lane];
                ax0 += e0 * hv0.x; ay0 += e0 * hv0.y;
                ax1 += e1 * hv1.x; ay1 += e1 * hv1.y;
                ax2 += e2 * hv2.x; ay2 += e2 * hv2.y;
                ax3 += e3 * hv3.x; ay3 += e3 * hv3.y;
            }
        } else {
            for (int j = 0; j < cnt; ++j) {
                int   src = __shfl(srci, j);
                float e   = __shfl(ex, j);
                float2 hv = h2v[(size_t)src * 64 + lane];
                ax0 += e * hv.x; ay0 += e * hv.y;
            }
        }
    }
    float ax = (ax0 + ax1) + (ax2 + ax3);
    float ay = (ay0 + ay1) + (ay2 + ay3);
    float scf = sv[i] + d_i; scf = scf > 0.f ? scf : NEG * scf;
    float exf = __expf(scf - m);
    float2 hv = h2v[(size_t)i * 64 + lane];
    ax += exf * hv.x; ay += exf * hv.y;
    #pragma unroll
    for (int o = 1; o < 64; o <<= 1) exs += __shfl_xor(exs, o);
    float rd = 1.f / (exs + exf);
    float2 b2 = *(const float2*)&bias[2 * lane];
    float2 o2 = make_float2(fmaxf(ax * rd + b2.x, 0.f), fmaxf(ay * rd + b2.y, 0.f));
    *(float2*)&out[(size_t)i * D + 2 * lane] = o2;
}

// ---------------- launcher -----------------------------------------------------
extern "C" void kernel_launch(void* const* d_in, const int* in_sizes, int n_in,
                              void* d_out, int out_size, void* d_ws, size_t ws_size,
                              hipStream_t stream) {
    const float* x   = (const float*)d_in[0];
    const int*   ei  = (const int*)d_in[1];
    const float* Ws  = (const float*)d_in[2];
    const float* as_ = (const float*)d_in[3];
    const float* ad_ = (const float*)d_in[4];
    const float* bs  = (const float*)d_in[5];
    float* out = (float*)d_out;
    int Eh = in_sizes[1] / 2;                    // 1,280,000

    char* ws = (char*)d_ws;
    float*    h2     = (float*)ws;                        //  2,560,000
    float*    bufS   = (float*)(ws + 2560000);            //  2,560,000
    float*    sv     = (float*)(ws + 5120000);            //     20,000
    float*    dv     = (float*)(ws + 5140000);            //     20,000
    int*      counts = (int*)  (ws + 5160000);            //     20,000
    int*      offs   = (int*)  (ws + 5180000);            //     20,016
    ushort_t* rank16 = (ushort_t*)(ws + 5200016);         //  2,560,000
    ushort_t* esrc   = (ushort_t*)(ws + 7760016);         //  2,560,000
    ushort_t* Wm     = (ushort_t*)(ws + 10320016);        //    196,608 (frag-major)
    uint_t*   gmaxu  = (uint_t*)(ws + 10528912);          //         12

    zero_kernel<<<(NODES_REAL + 255) / 256, 256, 0, stream>>>(counts, gmaxu);
    rank_kernel<<<(Eh + 255) / 256, 256, 0, stream>>>(ei, counts, rank16, Eh);
    scan_kernel<<<1, 1024, 0, stream>>>(counts, offs);
    scatter_det<<<(Eh + 255) / 256, 256, 0, stream>>>(ei, offs, rank16, esrc, Eh);
    wsplit_kernel<<<24, 256, 0, stream>>>(Ws, Wm);

    // rows >= 5000: fused 3-layer MLP (r4 structure), 3 grid slices of ~808
    // blocks each (~33us) so agg/gsmall/CSR surface in the profiler's top-5.
    {
        const int rows = NODES_TOTAL - NODES_REAL;           // 155,000
        const int nb   = (rows + 63) / 64;                   // 2,422
        const int nb1  = (nb + 2) / 3;                       // 808
        int base = NODES_REAL;
        for (int s = 0; s < 3; ++s) {
            int b0 = s * nb1;
            int bn = (s == 2) ? (nb - 2 * nb1) : nb1;
            if (bn <= 0) break;
            mlp3_kernel<<<bn, 256, 0, stream>>>(x, Wm, bs, out, base + b0 * 64);
        }
    }

    // rows < 5000: per-layer GAT pipeline
    for (int l = 0; l < 3; ++l) {
        const float* hin = (l == 0) ? x : bufS;
        float* hout = (l == 2) ? out : bufS;
        gsmall_kernel<<<(NODES_REAL + 15) / 16, 64, 0, stream>>>(
            hin, Wm + (size_t)l * WT2_L, as_ + l * D, ad_ + l * D, h2, sv, dv, gmaxu + l);
        agg_kernel<<<(NODES_REAL + 3) / 4, 256, 0, stream>>>(
            h2, sv, dv, offs, esrc, bs + l * D, hout, gmaxu + l);
    }
}

// Round 7
// 503.219 us; speedup vs baseline: 1.1256x; 1.0737x over previous
//
#include <hip/hip_runtime.h>
#include <math.h>

#define NODES_TOTAL 160000
#define NODES_REAL  5000
#define D 128
#define NEG 0.2f
#define KP2 128
#define HL2 (128 * KP2)       // ushorts per hi (or lo) block = 16384
#define WT2_L (2 * HL2)       // ushorts per layer (hi + lo)  = 32768 (64 KB)
#define CHUNK 16384           // edges per CSR chunk (2^14)

typedef unsigned short ushort_t;
typedef unsigned int uint_t;
typedef __attribute__((ext_vector_type(8))) __bf16 bf16x8;
typedef __attribute__((ext_vector_type(4))) float f32x4;
union BF8 { bf16x8 v; ushort_t u[8]; };

__device__ __forceinline__ void split2(float x, ushort_t& hi, ushort_t& lo) {
    unsigned u = __float_as_uint(x);
    hi = (ushort_t)(u >> 16);
    float hif = __uint_as_float(u & 0xffff0000u);
    lo = (ushort_t)(__float_as_uint(x - hif) >> 16);
}
__device__ __forceinline__ uint_t encmax(float f) {
    uint_t b = __float_as_uint(f);
    return b ^ ((uint_t)((int)b >> 31) | 0x80000000u);
}
__device__ __forceinline__ float decmax(uint_t u) {
    uint_t b = (u & 0x80000000u) ? (u ^ 0x80000000u) : ~u;
    return __uint_as_float(b);
}

// ---------------- CSR build (contention-free hierarchical) ---------------------
__global__ void zero_kernel(uint_t* gmaxu) {
    if (threadIdx.x < 3) gmaxu[threadIdx.x] = 0u;
}

// Per-chunk LDS histogram + local ranks. LDS atomics only (depth ~3/dst/chunk);
// histogram flushed with plain coalesced stores. NO global atomics.
__global__ __launch_bounds__(256)
void hist_rank_kernel(const int* __restrict__ ei, int* __restrict__ hist,
                      ushort_t* __restrict__ rank16, int Eh) {
    __shared__ uint_t lc[NODES_REAL];      // 20 KB
    int c = blockIdx.x, tid = threadIdx.x;
    for (int i = tid; i < NODES_REAL; i += 256) lc[i] = 0u;
    __syncthreads();
    int e0 = c * CHUNK;
    #pragma unroll 4
    for (int k = 0; k < CHUNK / 256; ++k) {
        int e = e0 + k * 256 + tid;
        if (e < Eh) {
            int d = ei[Eh + e];
            uint_t r = atomicAdd(&lc[d], 1u);
            rank16[e] = (ushort_t)r;
        }
    }
    __syncthreads();
    for (int i = tid; i < NODES_REAL; i += 256)
        hist[c * NODES_REAL + i] = (int)lc[i];
}

// counts[d] = sum over chunks of hist[c][d]  (coalesced column reads)
__global__ void colsum_kernel(const int* __restrict__ hist, int* __restrict__ counts,
                              int nchunks) {
    int d = blockIdx.x * 256 + threadIdx.x;
    if (d < NODES_REAL) {
        int s = 0;
        for (int c = 0; c < nchunks; ++c) s += hist[c * NODES_REAL + d];
        counts[d] = s;
    }
}

__global__ void scan_kernel(const int* __restrict__ counts, int* __restrict__ offs) {
    __shared__ int sd[1024];
    int t = threadIdx.x;
    int pre[5]; int sum = 0;
    #pragma unroll
    for (int u = 0; u < 5; ++u) {
        int idx = t * 5 + u;
        int c = (idx < NODES_REAL) ? counts[idx] : 0;
        pre[u] = sum; sum += c;
    }
    sd[t] = sum;
    __syncthreads();
    int run = sum;
    for (int o = 1; o < 1024; o <<= 1) {
        int v = (t >= o) ? sd[t - o] : 0;
        __syncthreads();
        sd[t] += v;
        __syncthreads();
    }
    int excl = sd[t] - run;
    #pragma unroll
    for (int u = 0; u < 5; ++u) {
        int idx = t * 5 + u;
        if (idx < NODES_REAL) offs[idx] = excl + pre[u];
    }
    if (t == 1023) offs[NODES_REAL] = excl + run;
}

// cbase[c][d] = offs[d] + prefix of hist over chunks (deterministic, no atomics)
__global__ void cbase_kernel(const int* __restrict__ hist, const int* __restrict__ offs,
                             int* __restrict__ cbase, int nchunks) {
    int d = blockIdx.x * 256 + threadIdx.x;
    if (d < NODES_REAL) {
        int run = offs[d];
        for (int c = 0; c < nchunks; ++c) {
            cbase[c * NODES_REAL + d] = run;
            run += hist[c * NODES_REAL + d];
        }
    }
}

__global__ void scatter_det(const int* __restrict__ ei, const int* __restrict__ cbase,
                            const ushort_t* __restrict__ rank16, ushort_t* __restrict__ esrc,
                            int Eh) {
    int e = blockIdx.x * blockDim.x + threadIdx.x;
    if (e < Eh) {
        int s = ei[e];
        int d = ei[Eh + e];
        int c = e >> 14;                   // e / CHUNK
        esrc[cbase[c * NODES_REAL + d] + (int)rank16[e]] = (ushort_t)s;
    }
}

// ---------------- W split+transpose -> fragment-major layout -------------------
// Wm: off(l,ct,kc,hl,lane) = l*WT2_L + ((ct*4+kc)*2+hl)*512 + lane*8
__global__ void wsplit_kernel(const float* __restrict__ Ws, ushort_t* __restrict__ Wm) {
    int l  = blockIdx.x >> 3;
    int n  = (blockIdx.x & 7) * 16 + (threadIdx.x >> 4);
    int c8 = threadIdx.x & 15;
    int k0 = c8 * 8;
    const float* src = Ws + (size_t)l * D * D;
    union { ushort_t u[8]; uint4 v; } hi, lo;
    #pragma unroll
    for (int j = 0; j < 8; ++j) split2(src[(size_t)(k0 + j) * D + n], hi.u[j], lo.u[j]);
    int ct = n >> 4, m16 = n & 15, kc = c8 >> 2, qq = c8 & 3;
    int lane = qq * 16 + m16;
    ushort_t* d2 = Wm + (size_t)l * WT2_L + ((ct * 4 + kc) * 2 + 0) * 512 + lane * 8;
    *(uint4*)d2 = hi.v;
    *(uint4*)(d2 + 512) = lo.v;     // hl=1
}

// ---------------- fused 3-layer MLP (round-4 structure, 2 grid slices) ---------
__global__ __launch_bounds__(256, 2)
void mlp3_kernel(const float* __restrict__ x, const ushort_t* __restrict__ Wm,
                 const float* __restrict__ bs, float* __restrict__ out, int row_base) {
    __shared__ float scr[2][2][16][132];   // 33792 B
    int tid = threadIdx.x;
    int w = tid >> 6, lane = tid & 63, q = lane >> 4, m16 = lane & 15;
    int p = w >> 1, h = w & 1;             // pair index, column-half index
    int row0 = row_base + blockIdx.x * 64 + p * 32;

    float4 xa[2][4][2];
    #pragma unroll
    for (int rt = 0; rt < 2; ++rt) {
        int r = row0 + rt * 16 + m16;
        if (r > NODES_TOTAL - 1) r = NODES_TOTAL - 1;
        #pragma unroll
        for (int kc = 0; kc < 4; ++kc) {
            const float* gp = x + (size_t)r * D + kc * 32 + q * 8;
            xa[rt][kc][0] = *(const float4*)gp;
            xa[rt][kc][1] = *(const float4*)(gp + 4);
        }
    }

    f32x4 acc[2][4];
    #pragma unroll
    for (int l = 0; l < 3; ++l) {
        const ushort_t* Wml = Wm + (size_t)l * WT2_L;
        if (l > 0) __syncthreads();        // (1) prev layer's scr writes visible

        BF8 ahi[2][4], alo[2][4];
        #pragma unroll
        for (int rt = 0; rt < 2; ++rt)
            #pragma unroll
            for (int kc = 0; kc < 4; ++kc) {
                float4 v0, v1;
                if (l == 0) { v0 = xa[rt][kc][0]; v1 = xa[rt][kc][1]; }
                else {
                    const float* sp = &scr[p][rt][m16][kc * 32 + q * 8];
                    v0 = *(const float4*)sp; v1 = *(const float4*)(sp + 4);
                }
                float xv[8] = {v0.x, v0.y, v0.z, v0.w, v1.x, v1.y, v1.z, v1.w};
                #pragma unroll
                for (int j = 0; j < 8; ++j) split2(xv[j], ahi[rt][kc].u[j], alo[rt][kc].u[j]);
            }
        if (l > 0) __syncthreads();        // (2) all scr reads done; writes below safe

        #pragma unroll
        for (int rt = 0; rt < 2; ++rt)
            #pragma unroll
            for (int ct = 0; ct < 4; ++ct) acc[rt][ct] = (f32x4){0.f, 0.f, 0.f, 0.f};

        #pragma unroll
        for (int ph = 0; ph < 2; ++ph) {
            int kc0 = ph * 2;
            bf16x8 bh[4][2], bl[4][2];
            #pragma unroll
            for (int ct = 0; ct < 4; ++ct)
                #pragma unroll
                for (int dk = 0; dk < 2; ++dk) {
                    const ushort_t* bp = Wml + (((h * 4 + ct) * 4 + (kc0 + dk)) * 2) * 512 + lane * 8;
                    bh[ct][dk] = *(const bf16x8*)bp;
                    bl[ct][dk] = *(const bf16x8*)(bp + 512);
                }
            #pragma unroll
            for (int dk = 0; dk < 2; ++dk)
                #pragma unroll
                for (int ct = 0; ct < 4; ++ct)
                    #pragma unroll
                    for (int rt = 0; rt < 2; ++rt) {
                        acc[rt][ct] = __builtin_amdgcn_mfma_f32_16x16x32_bf16(ahi[rt][kc0 + dk].v, bh[ct][dk], acc[rt][ct], 0, 0, 0);
                        acc[rt][ct] = __builtin_amdgcn_mfma_f32_16x16x32_bf16(ahi[rt][kc0 + dk].v, bl[ct][dk], acc[rt][ct], 0, 0, 0);
                        acc[rt][ct] = __builtin_amdgcn_mfma_f32_16x16x32_bf16(alo[rt][kc0 + dk].v, bh[ct][dk], acc[rt][ct], 0, 0, 0);
                    }
        }
        float bv[4];
        #pragma unroll
        for (int ct = 0; ct < 4; ++ct) bv[ct] = bs[l * D + (h * 4 + ct) * 16 + m16];
        #pragma unroll
        for (int rt = 0; rt < 2; ++rt)
            #pragma unroll
            for (int ct = 0; ct < 4; ++ct)
                #pragma unroll
                for (int reg = 0; reg < 4; ++reg)
                    scr[p][rt][q * 4 + reg][(h * 4 + ct) * 16 + m16] =
                        fmaxf(acc[rt][ct][reg] + bv[ct], 0.f);
    }
    __syncthreads();
    #pragma unroll
    for (int i = 0; i < 8; ++i) {
        int rowl = i * 2 + (lane >> 5);          // 0..15
        int grow = row0 + h * 16 + rowl;
        float4 v = *(const float4*)&scr[p][h][rowl][(lane & 31) * 4];
        if (grow < NODES_TOTAL)
            *(float4*)&out[(size_t)grow * D + (lane & 31) * 4] = v;
    }
}

// ---------------- small GEMM (rows<5000) + fused scores + per-layer max --------
__global__ __launch_bounds__(64, 2)
void gsmall_kernel(const float* __restrict__ hin, const ushort_t* __restrict__ Wm,
                   const float* __restrict__ a_s, const float* __restrict__ a_d,
                   float* __restrict__ h2, float* __restrict__ sv, float* __restrict__ dv,
                   uint_t* __restrict__ gmaxu) {
    int lane = threadIdx.x & 63, q = lane >> 4, m16 = lane & 15;
    int row0 = blockIdx.x * 16;
    float4 xa[4][2];
    {
        int r = row0 + m16;
        if (r > NODES_REAL - 1) r = NODES_REAL - 1;
        #pragma unroll
        for (int kc = 0; kc < 4; ++kc) {
            const float* gp = hin + (size_t)r * D + kc * 32 + q * 8;
            xa[kc][0] = *(const float4*)gp;
            xa[kc][1] = *(const float4*)(gp + 4);
        }
    }
    f32x4 acc[8];
    #pragma unroll
    for (int ct = 0; ct < 8; ++ct) acc[ct] = (f32x4){0.f, 0.f, 0.f, 0.f};

    #pragma unroll
    for (int kc = 0; kc < 4; ++kc) {
        BF8 ahi, alo;
        {
            float4 v0 = xa[kc][0], v1 = xa[kc][1];
            float xv[8] = {v0.x, v0.y, v0.z, v0.w, v1.x, v1.y, v1.z, v1.w};
            #pragma unroll
            for (int j = 0; j < 8; ++j) split2(xv[j], ahi.u[j], alo.u[j]);
        }
        bf16x8 bh[8], bl[8];
        #pragma unroll
        for (int ct = 0; ct < 8; ++ct) {
            const ushort_t* bp = Wm + ((ct * 4 + kc) * 2) * 512 + lane * 8;
            bh[ct] = *(const bf16x8*)bp;
            bl[ct] = *(const bf16x8*)(bp + 512);
        }
        #pragma unroll
        for (int ct = 0; ct < 8; ++ct) {
            acc[ct] = __builtin_amdgcn_mfma_f32_16x16x32_bf16(ahi.v, bh[ct], acc[ct], 0, 0, 0);
            acc[ct] = __builtin_amdgcn_mfma_f32_16x16x32_bf16(ahi.v, bl[ct], acc[ct], 0, 0, 0);
            acc[ct] = __builtin_amdgcn_mfma_f32_16x16x32_bf16(alo.v, bh[ct], acc[ct], 0, 0, 0);
        }
    }
    #pragma unroll
    for (int reg = 0; reg < 4; ++reg) {
        int grow = row0 + q * 4 + reg;
        if (grow < NODES_REAL) {
            #pragma unroll
            for (int ct = 0; ct < 8; ++ct)
                h2[(size_t)grow * D + ct * 16 + m16] = acc[ct][reg];
        }
    }
    float asv[8], adv[8];
    #pragma unroll
    for (int ct = 0; ct < 8; ++ct) { asv[ct] = a_s[ct * 16 + m16]; adv[ct] = a_d[ct * 16 + m16]; }
    #pragma unroll
    for (int reg = 0; reg < 4; ++reg) {
        float ps = 0.f, pd = 0.f;
        #pragma unroll
        for (int ct = 0; ct < 8; ++ct) {
            float v = acc[ct][reg];
            ps += v * asv[ct]; pd += v * adv[ct];
        }
        #pragma unroll
        for (int o = 1; o < 16; o <<= 1) { ps += __shfl_xor(ps, o); pd += __shfl_xor(pd, o); }
        int grow = row0 + q * 4 + reg;
        if (m16 == 0 && grow < NODES_REAL) {
            sv[grow] = ps; dv[grow] = pd;
            atomicMax(gmaxu, encmax(ps));
        }
    }
}

// ---------------- aggregation: one wave per dst, global-bound softmax ----------
__global__ __launch_bounds__(256)
void agg_kernel(const float* __restrict__ h2, const float* __restrict__ sv,
                const float* __restrict__ dv, const int* __restrict__ offs,
                const ushort_t* __restrict__ esrc, const float* __restrict__ bias,
                float* __restrict__ out, const uint_t* __restrict__ gmaxu) {
    int w = threadIdx.x >> 6, lane = threadIdx.x & 63;
    int i = blockIdx.x * 4 + w;
    int start = offs[i], end = offs[i + 1];
    float d_i = dv[i];
    float gm = decmax(*gmaxu) + d_i;
    float m = gm > 0.f ? gm : NEG * gm;
    const float2* h2v = (const float2*)h2;
    float ax0 = 0.f, ay0 = 0.f, ax1 = 0.f, ay1 = 0.f;
    float ax2 = 0.f, ay2 = 0.f, ax3 = 0.f, ay3 = 0.f, exs = 0.f;
    for (int base = start; base < end; base += 64) {
        int cnt = min(64, end - base);
        int srci = (lane < cnt) ? (int)esrc[base + lane] : 0;
        float sc = sv[srci] + d_i;
        sc = sc > 0.f ? sc : NEG * sc;
        float ex = (lane < cnt) ? __expf(sc - m) : 0.f;
        exs += ex;
        if (cnt == 64) {
            #pragma unroll 2
            for (int j = 0; j < 64; j += 4) {
                int   s0 = __shfl(srci, j),     s1 = __shfl(srci, j + 1);
                int   s2 = __shfl(srci, j + 2), s3 = __shfl(srci, j + 3);
                float e0 = __shfl(ex, j),       e1 = __shfl(ex, j + 1);
                float e2 = __shfl(ex, j + 2),   e3 = __shfl(ex, j + 3);
                float2 hv0 = h2v[(size_t)s0 * 64 + lane];
                float2 hv1 = h2v[(size_t)s1 * 64 + lane];
                float2 hv2 = h2v[(size_t)s2 * 64 + lane];
                float2 hv3 = h2v[(size_t)s3 * 64 + lane];
                ax0 += e0 * hv0.x; ay0 += e0 * hv0.y;
                ax1 += e1 * hv1.x; ay1 += e1 * hv1.y;
                ax2 += e2 * hv2.x; ay2 += e2 * hv2.y;
                ax3 += e3 * hv3.x; ay3 += e3 * hv3.y;
            }
        } else {
            for (int j = 0; j < cnt; ++j) {
                int   src = __shfl(srci, j);
                float e   = __shfl(ex, j);
                float2 hv = h2v[(size_t)src * 64 + lane];
                ax0 += e * hv.x; ay0 += e * hv.y;
            }
        }
    }
    float ax = (ax0 + ax1) + (ax2 + ax3);
    float ay = (ay0 + ay1) + (ay2 + ay3);
    float scf = sv[i] + d_i; scf = scf > 0.f ? scf : NEG * scf;
    float exf = __expf(scf - m);
    float2 hv = h2v[(size_t)i * 64 + lane];
    ax += exf * hv.x; ay += exf * hv.y;
    #pragma unroll
    for (int o = 1; o < 64; o <<= 1) exs += __shfl_xor(exs, o);
    float rd = 1.f / (exs + exf);
    float2 b2 = *(const float2*)&bias[2 * lane];
    float2 o2 = make_float2(fmaxf(ax * rd + b2.x, 0.f), fmaxf(ay * rd + b2.y, 0.f));
    *(float2*)&out[(size_t)i * D + 2 * lane] = o2;
}

// ---------------- launcher -----------------------------------------------------
extern "C" void kernel_launch(void* const* d_in, const int* in_sizes, int n_in,
                              void* d_out, int out_size, void* d_ws, size_t ws_size,
                              hipStream_t stream) {
    const float* x   = (const float*)d_in[0];
    const int*   ei  = (const int*)d_in[1];
    const float* Ws  = (const float*)d_in[2];
    const float* as_ = (const float*)d_in[3];
    const float* ad_ = (const float*)d_in[4];
    const float* bs  = (const float*)d_in[5];
    float* out = (float*)d_out;
    int Eh = in_sizes[1] / 2;                    // 1,280,000
    int nchunks = (Eh + CHUNK - 1) / CHUNK;      // 79

    char* ws = (char*)d_ws;
    float*    h2     = (float*)ws;                        //  2,560,000
    float*    bufS   = (float*)(ws + 2560000);            //  2,560,000
    float*    sv     = (float*)(ws + 5120000);            //     20,000
    float*    dv     = (float*)(ws + 5140000);            //     20,000
    int*      counts = (int*)  (ws + 5160000);            //     20,000
    int*      offs   = (int*)  (ws + 5180000);            //     20,016
    ushort_t* rank16 = (ushort_t*)(ws + 5200016);         //  2,560,000
    ushort_t* esrc   = (ushort_t*)(ws + 7760016);         //  2,560,000
    ushort_t* Wm     = (ushort_t*)(ws + 10320016);        //    196,608 (frag-major)
    uint_t*   gmaxu  = (uint_t*)(ws + 10528912);          //         12
    // CSR scratch aliases dead-at-build regions:
    int* hist  = (int*)h2;                                // 79*5000*4 = 1.58MB < 2.56MB
    int* cbase = (int*)bufS;                              // 1.58MB < 2.56MB

    zero_kernel<<<1, 64, 0, stream>>>(gmaxu);
    hist_rank_kernel<<<nchunks, 256, 0, stream>>>(ei, hist, rank16, Eh);
    colsum_kernel<<<(NODES_REAL + 255) / 256, 256, 0, stream>>>(hist, counts, nchunks);
    scan_kernel<<<1, 1024, 0, stream>>>(counts, offs);
    cbase_kernel<<<(NODES_REAL + 255) / 256, 256, 0, stream>>>(hist, offs, cbase, nchunks);
    scatter_det<<<(Eh + 255) / 256, 256, 0, stream>>>(ei, cbase, rank16, esrc, Eh);
    wsplit_kernel<<<24, 256, 0, stream>>>(Ws, Wm);

    // rows >= 5000: fused 3-layer MLP (r4 structure), 2 grid slices (~48us each)
    {
        const int rows = NODES_TOTAL - NODES_REAL;           // 155,000
        const int nb   = (rows + 63) / 64;                   // 2,422
        const int nb1  = (nb + 1) / 2;
        int base = NODES_REAL;
        for (int s = 0; s < 2; ++s) {
            int b0 = s * nb1;
            int bn = (s == 1) ? (nb - nb1) : nb1;
            if (bn <= 0) break;
            mlp3_kernel<<<bn, 256, 0, stream>>>(x, Wm, bs, out, base + b0 * 64);
        }
    }

    // rows < 5000: per-layer GAT pipeline
    for (int l = 0; l < 3; ++l) {
        const float* hin = (l == 0) ? x : bufS;
        float* hout = (l == 2) ? out : bufS;
        gsmall_kernel<<<(NODES_REAL + 15) / 16, 64, 0, stream>>>(
            hin, Wm + (size_t)l * WT2_L, as_ + l * D, ad_ + l * D, h2, sv, dv, gmaxu + l);
        agg_kernel<<<(NODES_REAL + 3) / 4, 256, 0, stream>>>(
            h2, sv, dv, offs, esrc, bs + l * D, hout, gmaxu + l);
    }
}

// Round 8
// 487.880 us; speedup vs baseline: 1.1610x; 1.0314x over previous
//
#include <hip/hip_runtime.h>
#include <math.h>

#define NODES_TOTAL 160000
#define NODES_REAL  5000
#define D 128
#define NEG 0.2f
#define KP2 128
#define HL2 (128 * KP2)       // ushorts per hi (or lo) block = 16384
#define WT2_L (2 * HL2)       // ushorts per layer (hi + lo)  = 32768 (64 KB)
#define CHUNK 16384           // edges per CSR chunk (2^14)

typedef unsigned short ushort_t;
typedef unsigned int uint_t;
typedef __attribute__((ext_vector_type(8))) __bf16 bf16x8;
typedef __attribute__((ext_vector_type(4))) float f32x4;
union BF8 { bf16x8 v; ushort_t u[8]; };

__device__ __forceinline__ void split2(float x, ushort_t& hi, ushort_t& lo) {
    unsigned u = __float_as_uint(x);
    hi = (ushort_t)(u >> 16);
    float hif = __uint_as_float(u & 0xffff0000u);
    lo = (ushort_t)(__float_as_uint(x - hif) >> 16);
}
__device__ __forceinline__ uint_t encmax(float f) {
    uint_t b = __float_as_uint(f);
    return b ^ ((uint_t)((int)b >> 31) | 0x80000000u);
}
__device__ __forceinline__ float decmax(uint_t u) {
    uint_t b = (u & 0x80000000u) ? (u ^ 0x80000000u) : ~u;
    return __uint_as_float(b);
}

// ---------------- W split + workspace zeroing (fused) --------------------------
// Wm: off(l,ct,kc,hl,lane) = l*WT2_L + ((ct*4+kc)*2+hl)*512 + lane*8
__global__ void wsplit_kernel(const float* __restrict__ Ws, ushort_t* __restrict__ Wm,
                              int* __restrict__ counts, uint_t* __restrict__ gmaxu) {
    int gid = blockIdx.x * 256 + threadIdx.x;
    if (gid < NODES_REAL) counts[gid] = 0;     // zeroed for rank2's atomic bases
    if (gid < 3) gmaxu[gid] = 0u;
    int l  = blockIdx.x >> 3;
    int n  = (blockIdx.x & 7) * 16 + (threadIdx.x >> 4);
    int c8 = threadIdx.x & 15;
    int k0 = c8 * 8;
    const float* src = Ws + (size_t)l * D * D;
    union { ushort_t u[8]; uint4 v; } hi, lo;
    #pragma unroll
    for (int j = 0; j < 8; ++j) split2(src[(size_t)(k0 + j) * D + n], hi.u[j], lo.u[j]);
    int ct = n >> 4, m16 = n & 15, kc = c8 >> 2, qq = c8 & 3;
    int lane = qq * 16 + m16;
    ushort_t* d2 = Wm + (size_t)l * WT2_L + ((ct * 4 + kc) * 2 + 0) * 512 + lane * 8;
    *(uint4*)d2 = hi.v;
    *(uint4*)(d2 + 512) = lo.v;     // hl=1
}

// ---------------- CSR: per-chunk LDS ranks + atomic block-base -----------------
// Local ranks via LDS atomics (depth ~3/dst/chunk). One global atomicAdd per
// (chunk,dst) — 395K atomics spread over 5000 addresses, depth 79 — returns the
// block's base directly. counts ends up as the full per-dst degree.
__global__ __launch_bounds__(256)
void rank2_kernel(const int* __restrict__ ei, int* __restrict__ counts,
                  int* __restrict__ bases, ushort_t* __restrict__ rank16, int Eh) {
    __shared__ uint_t lc[NODES_REAL];      // 20 KB
    int c = blockIdx.x, tid = threadIdx.x;
    for (int i = tid; i < NODES_REAL; i += 256) lc[i] = 0u;
    __syncthreads();
    int e0 = c * CHUNK;
    #pragma unroll 4
    for (int k = 0; k < CHUNK / 256; ++k) {
        int e = e0 + k * 256 + tid;
        if (e < Eh) {
            int d = ei[Eh + e];
            uint_t r = atomicAdd(&lc[d], 1u);
            rank16[e] = (ushort_t)r;
        }
    }
    __syncthreads();
    for (int i = tid; i < NODES_REAL; i += 256) {
        uint_t n = lc[i];
        if (n > 0u)
            bases[c * NODES_REAL + i] = atomicAdd(&counts[i], (int)n);
    }
}

__global__ void scan_kernel(const int* __restrict__ counts, int* __restrict__ offs) {
    __shared__ int sd[1024];
    int t = threadIdx.x;
    int pre[5]; int sum = 0;
    #pragma unroll
    for (int u = 0; u < 5; ++u) {
        int idx = t * 5 + u;
        int c = (idx < NODES_REAL) ? counts[idx] : 0;
        pre[u] = sum; sum += c;
    }
    sd[t] = sum;
    __syncthreads();
    int run = sum;
    for (int o = 1; o < 1024; o <<= 1) {
        int v = (t >= o) ? sd[t - o] : 0;
        __syncthreads();
        sd[t] += v;
        __syncthreads();
    }
    int excl = sd[t] - run;
    #pragma unroll
    for (int u = 0; u < 5; ++u) {
        int idx = t * 5 + u;
        if (idx < NODES_REAL) offs[idx] = excl + pre[u];
    }
    if (t == 1023) offs[NODES_REAL] = excl + run;
}

__global__ void scatter_det(const int* __restrict__ ei, const int* __restrict__ offs,
                            const int* __restrict__ bases,
                            const ushort_t* __restrict__ rank16, ushort_t* __restrict__ esrc,
                            int Eh) {
    int e = blockIdx.x * blockDim.x + threadIdx.x;
    if (e < Eh) {
        int s = ei[e];
        int d = ei[Eh + e];
        int c = e >> 14;                   // e / CHUNK
        esrc[offs[d] + bases[c * NODES_REAL + d] + (int)rank16[e]] = (ushort_t)s;
    }
}

// ---------------- fused 3-layer MLP (round-4 structure, single launch) ---------
__global__ __launch_bounds__(256, 2)
void mlp3_kernel(const float* __restrict__ x, const ushort_t* __restrict__ Wm,
                 const float* __restrict__ bs, float* __restrict__ out) {
    __shared__ float scr[2][2][16][132];   // 33792 B
    int tid = threadIdx.x;
    int w = tid >> 6, lane = tid & 63, q = lane >> 4, m16 = lane & 15;
    int p = w >> 1, h = w & 1;             // pair index, column-half index
    int row0 = NODES_REAL + blockIdx.x * 64 + p * 32;

    float4 xa[2][4][2];
    #pragma unroll
    for (int rt = 0; rt < 2; ++rt) {
        int r = row0 + rt * 16 + m16;
        if (r > NODES_TOTAL - 1) r = NODES_TOTAL - 1;
        #pragma unroll
        for (int kc = 0; kc < 4; ++kc) {
            const float* gp = x + (size_t)r * D + kc * 32 + q * 8;
            xa[rt][kc][0] = *(const float4*)gp;
            xa[rt][kc][1] = *(const float4*)(gp + 4);
        }
    }

    f32x4 acc[2][4];
    #pragma unroll
    for (int l = 0; l < 3; ++l) {
        const ushort_t* Wml = Wm + (size_t)l * WT2_L;
        if (l > 0) __syncthreads();        // (1) prev layer's scr writes visible

        BF8 ahi[2][4], alo[2][4];
        #pragma unroll
        for (int rt = 0; rt < 2; ++rt)
            #pragma unroll
            for (int kc = 0; kc < 4; ++kc) {
                float4 v0, v1;
                if (l == 0) { v0 = xa[rt][kc][0]; v1 = xa[rt][kc][1]; }
                else {
                    const float* sp = &scr[p][rt][m16][kc * 32 + q * 8];
                    v0 = *(const float4*)sp; v1 = *(const float4*)(sp + 4);
                }
                float xv[8] = {v0.x, v0.y, v0.z, v0.w, v1.x, v1.y, v1.z, v1.w};
                #pragma unroll
                for (int j = 0; j < 8; ++j) split2(xv[j], ahi[rt][kc].u[j], alo[rt][kc].u[j]);
            }
        if (l > 0) __syncthreads();        // (2) all scr reads done; writes below safe

        #pragma unroll
        for (int rt = 0; rt < 2; ++rt)
            #pragma unroll
            for (int ct = 0; ct < 4; ++ct) acc[rt][ct] = (f32x4){0.f, 0.f, 0.f, 0.f};

        #pragma unroll
        for (int ph = 0; ph < 2; ++ph) {
            int kc0 = ph * 2;
            bf16x8 bh[4][2], bl[4][2];
            #pragma unroll
            for (int ct = 0; ct < 4; ++ct)
                #pragma unroll
                for (int dk = 0; dk < 2; ++dk) {
                    const ushort_t* bp = Wml + (((h * 4 + ct) * 4 + (kc0 + dk)) * 2) * 512 + lane * 8;
                    bh[ct][dk] = *(const bf16x8*)bp;
                    bl[ct][dk] = *(const bf16x8*)(bp + 512);
                }
            #pragma unroll
            for (int dk = 0; dk < 2; ++dk)
                #pragma unroll
                for (int ct = 0; ct < 4; ++ct)
                    #pragma unroll
                    for (int rt = 0; rt < 2; ++rt) {
                        acc[rt][ct] = __builtin_amdgcn_mfma_f32_16x16x32_bf16(ahi[rt][kc0 + dk].v, bh[ct][dk], acc[rt][ct], 0, 0, 0);
                        acc[rt][ct] = __builtin_amdgcn_mfma_f32_16x16x32_bf16(ahi[rt][kc0 + dk].v, bl[ct][dk], acc[rt][ct], 0, 0, 0);
                        acc[rt][ct] = __builtin_amdgcn_mfma_f32_16x16x32_bf16(alo[rt][kc0 + dk].v, bh[ct][dk], acc[rt][ct], 0, 0, 0);
                    }
        }
        float bv[4];
        #pragma unroll
        for (int ct = 0; ct < 4; ++ct) bv[ct] = bs[l * D + (h * 4 + ct) * 16 + m16];
        #pragma unroll
        for (int rt = 0; rt < 2; ++rt)
            #pragma unroll
            for (int ct = 0; ct < 4; ++ct)
                #pragma unroll
                for (int reg = 0; reg < 4; ++reg)
                    scr[p][rt][q * 4 + reg][(h * 4 + ct) * 16 + m16] =
                        fmaxf(acc[rt][ct][reg] + bv[ct], 0.f);
    }
    __syncthreads();
    #pragma unroll
    for (int i = 0; i < 8; ++i) {
        int rowl = i * 2 + (lane >> 5);          // 0..15
        int grow = row0 + h * 16 + rowl;
        float4 v = *(const float4*)&scr[p][h][rowl][(lane & 31) * 4];
        if (grow < NODES_TOTAL)
            *(float4*)&out[(size_t)grow * D + (lane & 31) * 4] = v;
    }
}

// ---------------- small GEMM (rows<5000) + fused scores + per-layer max --------
__global__ __launch_bounds__(64, 2)
void gsmall_kernel(const float* __restrict__ hin, const ushort_t* __restrict__ Wm,
                   const float* __restrict__ a_s, const float* __restrict__ a_d,
                   float* __restrict__ h2, float* __restrict__ sv, float* __restrict__ dv,
                   uint_t* __restrict__ gmaxu) {
    int lane = threadIdx.x & 63, q = lane >> 4, m16 = lane & 15;
    int row0 = blockIdx.x * 16;
    float4 xa[4][2];
    {
        int r = row0 + m16;
        if (r > NODES_REAL - 1) r = NODES_REAL - 1;
        #pragma unroll
        for (int kc = 0; kc < 4; ++kc) {
            const float* gp = hin + (size_t)r * D + kc * 32 + q * 8;
            xa[kc][0] = *(const float4*)gp;
            xa[kc][1] = *(const float4*)(gp + 4);
        }
    }
    f32x4 acc[8];
    #pragma unroll
    for (int ct = 0; ct < 8; ++ct) acc[ct] = (f32x4){0.f, 0.f, 0.f, 0.f};

    #pragma unroll
    for (int kc = 0; kc < 4; ++kc) {
        BF8 ahi, alo;
        {
            float4 v0 = xa[kc][0], v1 = xa[kc][1];
            float xv[8] = {v0.x, v0.y, v0.z, v0.w, v1.x, v1.y, v1.z, v1.w};
            #pragma unroll
            for (int j = 0; j < 8; ++j) split2(xv[j], ahi.u[j], alo.u[j]);
        }
        bf16x8 bh[8], bl[8];
        #pragma unroll
        for (int ct = 0; ct < 8; ++ct) {
            const ushort_t* bp = Wm + ((ct * 4 + kc) * 2) * 512 + lane * 8;
            bh[ct] = *(const bf16x8*)bp;
            bl[ct] = *(const bf16x8*)(bp + 512);
        }
        #pragma unroll
        for (int ct = 0; ct < 8; ++ct) {
            acc[ct] = __builtin_amdgcn_mfma_f32_16x16x32_bf16(ahi.v, bh[ct], acc[ct], 0, 0, 0);
            acc[ct] = __builtin_amdgcn_mfma_f32_16x16x32_bf16(ahi.v, bl[ct], acc[ct], 0, 0, 0);
            acc[ct] = __builtin_amdgcn_mfma_f32_16x16x32_bf16(alo.v, bh[ct], acc[ct], 0, 0, 0);
        }
    }
    #pragma unroll
    for (int reg = 0; reg < 4; ++reg) {
        int grow = row0 + q * 4 + reg;
        if (grow < NODES_REAL) {
            #pragma unroll
            for (int ct = 0; ct < 8; ++ct)
                h2[(size_t)grow * D + ct * 16 + m16] = acc[ct][reg];
        }
    }
    float asv[8], adv[8];
    #pragma unroll
    for (int ct = 0; ct < 8; ++ct) { asv[ct] = a_s[ct * 16 + m16]; adv[ct] = a_d[ct * 16 + m16]; }
    #pragma unroll
    for (int reg = 0; reg < 4; ++reg) {
        float ps = 0.f, pd = 0.f;
        #pragma unroll
        for (int ct = 0; ct < 8; ++ct) {
            float v = acc[ct][reg];
            ps += v * asv[ct]; pd += v * adv[ct];
        }
        #pragma unroll
        for (int o = 1; o < 16; o <<= 1) { ps += __shfl_xor(ps, o); pd += __shfl_xor(pd, o); }
        int grow = row0 + q * 4 + reg;
        if (m16 == 0 && grow < NODES_REAL) {
            sv[grow] = ps; dv[grow] = pd;
            atomicMax(gmaxu, encmax(ps));
        }
    }
}

// ---------------- aggregation: one wave per dst, pipelined gather --------------
__global__ __launch_bounds__(256)
void agg_kernel(const float* __restrict__ h2, const float* __restrict__ sv,
                const float* __restrict__ dv, const int* __restrict__ offs,
                const ushort_t* __restrict__ esrc, const float* __restrict__ bias,
                float* __restrict__ out, const uint_t* __restrict__ gmaxu) {
    int w = threadIdx.x >> 6, lane = threadIdx.x & 63;
    int i = blockIdx.x * 4 + w;
    int start = offs[i], end = offs[i + 1];
    float d_i = dv[i];
    float gm = decmax(*gmaxu) + d_i;
    float m = gm > 0.f ? gm : NEG * gm;
    const float2* h2v = (const float2*)h2;
    float ax0 = 0.f, ay0 = 0.f, ax1 = 0.f, ay1 = 0.f;
    float ax2 = 0.f, ay2 = 0.f, ax3 = 0.f, ay3 = 0.f, exs = 0.f;
    for (int base = start; base < end; base += 64) {
        int cnt = min(64, end - base);
        int srci = (lane < cnt) ? (int)esrc[base + lane] : 0;
        float sc = sv[srci] + d_i;
        sc = sc > 0.f ? sc : NEG * sc;
        float ex = (lane < cnt) ? __expf(sc - m) : 0.f;
        exs += ex;
        if (cnt == 64) {
            // 2-stage pipeline: prefetch quad j+4 while fmac'ing quad j
            float e0 = __shfl(ex, 0), e1 = __shfl(ex, 1);
            float e2 = __shfl(ex, 2), e3 = __shfl(ex, 3);
            float2 hv0 = h2v[(size_t)__shfl(srci, 0) * 64 + lane];
            float2 hv1 = h2v[(size_t)__shfl(srci, 1) * 64 + lane];
            float2 hv2 = h2v[(size_t)__shfl(srci, 2) * 64 + lane];
            float2 hv3 = h2v[(size_t)__shfl(srci, 3) * 64 + lane];
            for (int j = 4; j < 64; j += 4) {
                float f0 = __shfl(ex, j),     f1 = __shfl(ex, j + 1);
                float f2 = __shfl(ex, j + 2), f3 = __shfl(ex, j + 3);
                float2 nv0 = h2v[(size_t)__shfl(srci, j) * 64 + lane];
                float2 nv1 = h2v[(size_t)__shfl(srci, j + 1) * 64 + lane];
                float2 nv2 = h2v[(size_t)__shfl(srci, j + 2) * 64 + lane];
                float2 nv3 = h2v[(size_t)__shfl(srci, j + 3) * 64 + lane];
                ax0 += e0 * hv0.x; ay0 += e0 * hv0.y;
                ax1 += e1 * hv1.x; ay1 += e1 * hv1.y;
                ax2 += e2 * hv2.x; ay2 += e2 * hv2.y;
                ax3 += e3 * hv3.x; ay3 += e3 * hv3.y;
                e0 = f0; e1 = f1; e2 = f2; e3 = f3;
                hv0 = nv0; hv1 = nv1; hv2 = nv2; hv3 = nv3;
            }
            ax0 += e0 * hv0.x; ay0 += e0 * hv0.y;
            ax1 += e1 * hv1.x; ay1 += e1 * hv1.y;
            ax2 += e2 * hv2.x; ay2 += e2 * hv2.y;
            ax3 += e3 * hv3.x; ay3 += e3 * hv3.y;
        } else {
            for (int j = 0; j < cnt; ++j) {
                int   src = __shfl(srci, j);
                float e   = __shfl(ex, j);
                float2 hv = h2v[(size_t)src * 64 + lane];
                ax0 += e * hv.x; ay0 += e * hv.y;
            }
        }
    }
    float ax = (ax0 + ax1) + (ax2 + ax3);
    float ay = (ay0 + ay1) + (ay2 + ay3);
    float scf = sv[i] + d_i; scf = scf > 0.f ? scf : NEG * scf;
    float exf = __expf(scf - m);
    float2 hv = h2v[(size_t)i * 64 + lane];
    ax += exf * hv.x; ay += exf * hv.y;
    #pragma unroll
    for (int o = 1; o < 64; o <<= 1) exs += __shfl_xor(exs, o);
    float rd = 1.f / (exs + exf);
    float2 b2 = *(const float2*)&bias[2 * lane];
    float2 o2 = make_float2(fmaxf(ax * rd + b2.x, 0.f), fmaxf(ay * rd + b2.y, 0.f));
    *(float2*)&out[(size_t)i * D + 2 * lane] = o2;
}

// ---------------- launcher -----------------------------------------------------
extern "C" void kernel_launch(void* const* d_in, const int* in_sizes, int n_in,
                              void* d_out, int out_size, void* d_ws, size_t ws_size,
                              hipStream_t stream) {
    const float* x   = (const float*)d_in[0];
    const int*   ei  = (const int*)d_in[1];
    const float* Ws  = (const float*)d_in[2];
    const float* as_ = (const float*)d_in[3];
    const float* ad_ = (const float*)d_in[4];
    const float* bs  = (const float*)d_in[5];
    float* out = (float*)d_out;
    int Eh = in_sizes[1] / 2;                    // 1,280,000
    int nchunks = (Eh + CHUNK - 1) / CHUNK;      // 79

    char* ws = (char*)d_ws;
    float*    h2     = (float*)ws;                        //  2,560,000
    float*    bufS   = (float*)(ws + 2560000);            //  2,560,000
    float*    sv     = (float*)(ws + 5120000);            //     20,000
    float*    dv     = (float*)(ws + 5140000);            //     20,000
    int*      counts = (int*)  (ws + 5160000);            //     20,000
    int*      offs   = (int*)  (ws + 5180000);            //     20,016
    ushort_t* rank16 = (ushort_t*)(ws + 5200016);         //  2,560,000
    ushort_t* esrc   = (ushort_t*)(ws + 7760016);         //  2,560,000
    ushort_t* Wm     = (ushort_t*)(ws + 10320016);        //    196,608 (frag-major)
    uint_t*   gmaxu  = (uint_t*)(ws + 10528912);          //         12
    int*      bases  = (int*)h2;   // 79*5000*4 = 1.58MB, dead during CSR build

    // 11 launches total (was 15): wsplit(+zero), rank2, scan, scatter, mlp3,
    // 3x(gsmall, agg).
    wsplit_kernel<<<24, 256, 0, stream>>>(Ws, Wm, counts, gmaxu);
    rank2_kernel<<<nchunks, 256, 0, stream>>>(ei, counts, bases, rank16, Eh);
    scan_kernel<<<1, 1024, 0, stream>>>(counts, offs);
    scatter_det<<<(Eh + 255) / 256, 256, 0, stream>>>(ei, offs, bases, rank16, esrc, Eh);

    // rows >= 5000: fused 3-layer MLP, one HBM pass, single launch (r4-verified)
    mlp3_kernel<<<(NODES_TOTAL - NODES_REAL + 63) / 64, 256, 0, stream>>>(x, Wm, bs, out);

    // rows < 5000: per-layer GAT pipeline
    for (int l = 0; l < 3; ++l) {
        const float* hin = (l == 0) ? x : bufS;
        float* hout = (l == 2) ? out : bufS;
        gsmall_kernel<<<(NODES_REAL + 15) / 16, 64, 0, stream>>>(
            hin, Wm + (size_t)l * WT2_L, as_ + l * D, ad_ + l * D, h2, sv, dv, gmaxu + l);
        agg_kernel<<<(NODES_REAL + 3) / 4, 256, 0, stream>>>(
            h2, sv, dv, offs, esrc, bs + l * D, hout, gmaxu + l);
    }
}